// Round 8
// baseline (883.244 us; speedup 1.0000x reference)
//
#include <hip/hip_runtime.h>

typedef unsigned short u16;
typedef unsigned int u32;
typedef __bf16 bf16x8 __attribute__((ext_vector_type(8)));
typedef float f32x4 __attribute__((ext_vector_type(4)));

constexpr int Bn = 8, Tn = 2048, En = 1024, Hn = 64;
constexpr int Mrows = Bn * Tn;  // 16384
// softmax in exp2 domain: fold E^-0.5 * log2(e) into q pre-scale
constexpr float SCALE_LOG2E = 0.03125f * 1.4426950408889634f;

// ---- dtype sniff: packed bf16 vs fp32 (bf16 exponent bits land in [96,144]) ----
__device__ __forceinline__ bool sniff_bf16(const u32* xw) {
  int cnt = 0;
#pragma unroll 1
  for (int i = 0; i < 64; ++i) {
    u32 e = (xw[i] >> 7) & 0xFFu;
    cnt += (e >= 96u && e <= 144u) ? 1 : 0;
  }
  return cnt >= 48;
}

__device__ __forceinline__ u16 f2bf(float f) {  // RNE f32 -> bf16
  u32 u = __float_as_uint(f);
  return (u16)((u + 0x7fffu + ((u >> 16) & 1u)) >> 16);
}

// ---------- phase 0: W [E][H] -> Wt [3][H][E] bf16 (contiguous-k A-frags) ----------
__global__ void wt_kernel(const void* __restrict__ xv, const void* __restrict__ Wkv,
                          const void* __restrict__ Wqv, const void* __restrict__ Wvv,
                          u16* __restrict__ Wt) {
  const bool isbf = sniff_bf16((const u32*)xv);
  int tid = blockIdx.x * 256 + threadIdx.x;  // 3*64*1024 = 196608 exact
  int mat = tid >> 16;
  int rem = tid & 65535;
  int h = rem >> 10, k = rem & 1023;
  const void* W = (mat == 0) ? Wkv : (mat == 1) ? Wqv : Wvv;
  u16 val;
  if (isbf) val = ((const u16*)W)[k * 64 + h];
  else      val = f2bf(((const float*)W)[k * 64 + h]);
  Wt[tid] = val;
}

// ---------- phase 1: QKV projection via mfma_f32_16x16x32_bf16 (PROVEN R7) ----------
__global__ __launch_bounds__(256, 1) void qkv_kernel(
    const void* __restrict__ xv, const u16* __restrict__ Wt,
    float* __restrict__ K, float* __restrict__ Q, float* __restrict__ V) {
  const bool isbf = sniff_bf16((const u32*)xv);
  const int w = threadIdx.x >> 6, lane = threadIdx.x & 63;
  const int quad = lane >> 4, l16 = lane & 15;
  const int r0 = blockIdx.x * 64 + w * 16;
  const u16* wp = Wt + (size_t)l16 * En + quad * 8;
  f32x4 acc[12];
  f32x4 zero = {0.f, 0.f, 0.f, 0.f};
#pragma unroll
  for (int i = 0; i < 12; ++i) acc[i] = zero;

  if (isbf) {
    const u16* xp = (const u16*)xv + (size_t)(r0 + l16) * En + quad * 8;
    for (int k0 = 0; k0 < En; k0 += 32) {
      bf16x8 bfr = *(const bf16x8*)(xp + k0);
#pragma unroll
      for (int mt = 0; mt < 12; ++mt) {
        bf16x8 afr = *(const bf16x8*)(wp + (size_t)(mt * 16) * En + k0);
        acc[mt] = __builtin_amdgcn_mfma_f32_16x16x32_bf16(afr, bfr, acc[mt], 0, 0, 0);
      }
    }
  } else {
    const float* xp = (const float*)xv + (size_t)(r0 + l16) * En + quad * 8;
    for (int k0 = 0; k0 < En; k0 += 32) {
      float4 f0 = *(const float4*)(xp + k0);
      float4 f1 = *(const float4*)(xp + k0 + 4);
      bf16x8 bfr;
      bfr[0] = (__bf16)f0.x; bfr[1] = (__bf16)f0.y;
      bfr[2] = (__bf16)f0.z; bfr[3] = (__bf16)f0.w;
      bfr[4] = (__bf16)f1.x; bfr[5] = (__bf16)f1.y;
      bfr[6] = (__bf16)f1.z; bfr[7] = (__bf16)f1.w;
#pragma unroll
      for (int mt = 0; mt < 12; ++mt) {
        bf16x8 afr = *(const bf16x8*)(wp + (size_t)(mt * 16) * En + k0);
        acc[mt] = __builtin_amdgcn_mfma_f32_16x16x32_bf16(afr, bfr, acc[mt], 0, 0, 0);
      }
    }
  }

  float* outs[3] = {K, Q, V};
  const int row = r0 + l16;
#pragma unroll
  for (int mt = 0; mt < 12; ++mt) {
    float* dst = outs[mt >> 2] + (size_t)row * Hn + (mt & 3) * 16 + quad * 4;
    *(f32x4*)dst = acc[mt];
  }
}

// ---------- phase 2 (R8): flash attention, lane = (query, dim-quarter) ----------
// Fixes R7's register spill (q[64]+o[64] -> q[16]+o[16]): VGPR ~90, no scratch.
// Block = 256 thr = 4 waves on ONE 16-query tile, 4-way key split, LDS combine
// (combine algebra identical to R7/R5 verified versions). Grid ordered big-tile-
// first to fill the causal imbalance.
__global__ __launch_bounds__(256, 4) void attn_kernel(
    const float* __restrict__ Q, const float* __restrict__ K,
    const float* __restrict__ V, float* __restrict__ out) {
  const int idx = blockIdx.x;
  const int b = idx & 7;
  const int t = 127 - (idx >> 3);            // tile 127 (2048 keys) dispatched first
  const int w = threadIdx.x >> 6, lane = threadIdx.x & 63;
  const int ql = lane >> 2, hq = lane & 3;   // query-in-tile, dim quarter
  const int q_abs = t * 16 + ql;
  const int limit = t * 16 + 16;             // keys needed by this tile
  const int ch = ((t + 4) >> 2) * 16;        // per-wave key chunk (mult of 16)
  const int lo = w * ch;
  const int hi_l = min(min(lo + ch, limit), q_abs + 1);  // per-lane causal bound
  const float* Kb = K + (size_t)b * Tn * Hn;
  const float* Vb = V + (size_t)b * Tn * Hn;

  float qr[16], o[16];
  {
    const float4* qp = (const float4*)(Q + ((size_t)b * Tn + q_abs) * Hn + hq * 16);
#pragma unroll
    for (int i = 0; i < 4; ++i) {
      float4 v = qp[i];
      qr[4 * i + 0] = v.x * SCALE_LOG2E;
      qr[4 * i + 1] = v.y * SCALE_LOG2E;
      qr[4 * i + 2] = v.z * SCALE_LOG2E;
      qr[4 * i + 3] = v.w * SCALE_LOG2E;
    }
  }
#pragma unroll
  for (int i = 0; i < 16; ++i) o[i] = 0.f;
  float m = -3.0e38f, l = 0.f;

  for (int j = lo; j < hi_l; ++j) {
    const float4* kr = (const float4*)(Kb + (size_t)j * Hn + hq * 16);
    float s = 0.f;
#pragma unroll
    for (int i = 0; i < 4; ++i) {
      float4 kk = kr[i];
      s += qr[4 * i + 0] * kk.x;
      s += qr[4 * i + 1] * kk.y;
      s += qr[4 * i + 2] * kk.z;
      s += qr[4 * i + 3] * kk.w;
    }
    s += __shfl_xor(s, 1);   // sum the 4 dim-quarters of this query
    s += __shfl_xor(s, 2);
    const float mn = fmaxf(m, s);
    const float c = __builtin_amdgcn_exp2f(m - mn);  // first iter: exp2(-inf)=0
    const float e = __builtin_amdgcn_exp2f(s - mn);
    l = l * c + e;
    const float4* vr = (const float4*)(Vb + (size_t)j * Hn + hq * 16);
#pragma unroll
    for (int i = 0; i < 4; ++i) {
      float4 vv = vr[i];
      o[4 * i + 0] = o[4 * i + 0] * c + e * vv.x;
      o[4 * i + 1] = o[4 * i + 1] * c + e * vv.y;
      o[4 * i + 2] = o[4 * i + 2] * c + e * vv.z;
      o[4 * i + 3] = o[4 * i + 3] * c + e * vv.w;
    }
    m = mn;
  }

  // ---- cross-wave combine in LDS (same algebra as verified R7 combine) ----
  __shared__ float m_sh[4][16];
  __shared__ float l_sh[4][16];
  __shared__ float o_sh[4][16][64];
  if (hq == 0) { m_sh[w][ql] = m; l_sh[w][ql] = l; }
#pragma unroll
  for (int i = 0; i < 16; ++i) o_sh[w][ql][hq * 16 + i] = o[i];
  __syncthreads();

  // thread -> (query qq = tid>>4, dim group dq = tid&15 -> 4 dims)
  const int qq = threadIdx.x >> 4, dq = threadIdx.x & 15;
  float mg = m_sh[0][qq];
#pragma unroll
  for (int ww = 1; ww < 4; ++ww) mg = fmaxf(mg, m_sh[ww][qq]);
  float lg = 0.f;
  float acc[4] = {0.f, 0.f, 0.f, 0.f};
#pragma unroll
  for (int ww = 0; ww < 4; ++ww) {
    const float lw = l_sh[ww][qq];
    if (lw > 0.f) {
      const float a = __builtin_amdgcn_exp2f(m_sh[ww][qq] - mg);
      lg += a * lw;
#pragma unroll
      for (int i = 0; i < 4; ++i) acc[i] += a * o_sh[ww][qq][dq * 4 + i];
    }
  }
  const float inv = 1.f / lg;
  float4 res;
  res.x = acc[0] * inv; res.y = acc[1] * inv;
  res.z = acc[2] * inv; res.w = acc[3] * inv;
  *(float4*)(out + ((size_t)b * Tn + t * 16 + qq) * Hn + dq * 4) = res;
}

extern "C" void kernel_launch(void* const* d_in, const int* in_sizes, int n_in,
                              void* d_out, int out_size, void* d_ws, size_t ws_size,
                              hipStream_t stream) {
  // Order-agnostic input mapping (R4 proved it selects the documented order).
  const void* x = nullptr;
  const void* Ws[3] = {nullptr, nullptr, nullptr};
  int wj = 0;
  for (int i = 0; i < n_in; ++i) {
    if (in_sizes[i] == Bn * Tn * En) x = d_in[i];
    else if (wj < 3) Ws[wj++] = d_in[i];
  }
  const void* Wk = Ws[0];
  const void* Wq = Ws[1];
  const void* Wv = Ws[2];

  // ws: Q,K,V fp32 [16384][64] (4 MB each) + Wt bf16 (384 KB). Fits (R2==R3 proof).
  float* Qf = (float*)d_ws;
  float* Kf = Qf + (size_t)Mrows * Hn;
  float* Vf = Kf + (size_t)Mrows * Hn;
  u16* Wt = (u16*)(Vf + (size_t)Mrows * Hn);

  wt_kernel<<<768, 256, 0, stream>>>(x, Wk, Wq, Wv, Wt);
  qkv_kernel<<<Mrows / 64, 256, 0, stream>>>(x, Wt, Kf, Qf, Vf);
  attn_kernel<<<Bn * (Tn / 16), 256, 0, stream>>>(Qf, Kf, Vf, (float*)d_out);
}

// Round 9
// 724.231 us; speedup vs baseline: 1.2196x; 1.2196x over previous
//
#include <hip/hip_runtime.h>

typedef unsigned short u16;
typedef unsigned int u32;
typedef __bf16 bf16x8 __attribute__((ext_vector_type(8)));
typedef float f32x4 __attribute__((ext_vector_type(4)));

constexpr int Bn = 8, Tn = 2048, En = 1024, Hn = 64;
constexpr int Mrows = Bn * Tn;  // 16384
// softmax in exp2 domain: fold E^-0.5 * log2(e) into q pre-scale
constexpr float SCALE_LOG2E = 0.03125f * 1.4426950408889634f;

// ---- dtype sniff: packed bf16 vs fp32 (bf16 exponent bits land in [96,144]) ----
__device__ __forceinline__ bool sniff_bf16(const u32* xw) {
  int cnt = 0;
#pragma unroll 1
  for (int i = 0; i < 64; ++i) {
    u32 e = (xw[i] >> 7) & 0xFFu;
    cnt += (e >= 96u && e <= 144u) ? 1 : 0;
  }
  return cnt >= 48;
}

__device__ __forceinline__ u16 f2bf(float f) {  // RNE f32 -> bf16
  u32 u = __float_as_uint(f);
  return (u16)((u + 0x7fffu + ((u >> 16) & 1u)) >> 16);
}

// ---------- phase 0: W [E][H] -> Wt [3][H][E] bf16 (contiguous-k A-frags) ----------
__global__ void wt_kernel(const void* __restrict__ xv, const void* __restrict__ Wkv,
                          const void* __restrict__ Wqv, const void* __restrict__ Wvv,
                          u16* __restrict__ Wt) {
  const bool isbf = sniff_bf16((const u32*)xv);
  int tid = blockIdx.x * 256 + threadIdx.x;  // 3*64*1024 = 196608 exact
  int mat = tid >> 16;
  int rem = tid & 65535;
  int h = rem >> 10, k = rem & 1023;
  const void* W = (mat == 0) ? Wkv : (mat == 1) ? Wqv : Wvv;
  u16 val;
  if (isbf) val = ((const u16*)W)[k * 64 + h];
  else      val = f2bf(((const float*)W)[k * 64 + h]);
  Wt[tid] = val;
}

// ---------- phase 1 (R9): QKV projection, mat-split for occupancy ----------
// One wave (64-thr block) per (16-row group, matrix): grid 3072 -> 12 waves/CU
// (was 256 blocks = 4 waves/CU). Interleaved mat-minor so all 3 mats' reads of
// the same x rows co-run (L2/L3 reuse). MFMA mapping identical to proven R7.
__global__ __launch_bounds__(64, 1) void qkv_kernel(
    const void* __restrict__ xv, const u16* __restrict__ Wt,
    float* __restrict__ K, float* __restrict__ Q, float* __restrict__ V) {
  const bool isbf = sniff_bf16((const u32*)xv);
  const u32 bx = blockIdx.x;
  const u32 rg = bx / 3u;        // row group 0..1023
  const u32 mat = bx - rg * 3u;  // 0..2
  const int lane = threadIdx.x;
  const int quad = lane >> 4, l16 = lane & 15;
  const int r0 = rg * 16;
  const u16* wp = Wt + (size_t)mat * (Hn * En) + (size_t)l16 * En + quad * 8;
  f32x4 acc0 = {0.f, 0.f, 0.f, 0.f}, acc1 = acc0, acc2 = acc0, acc3 = acc0;

  if (isbf) {
    const u16* xp = (const u16*)xv + (size_t)(r0 + l16) * En + quad * 8;
    for (int k0 = 0; k0 < En; k0 += 32) {
      bf16x8 bfr = *(const bf16x8*)(xp + k0);
      bf16x8 a0 = *(const bf16x8*)(wp + k0);
      bf16x8 a1 = *(const bf16x8*)(wp + (size_t)(16) * En + k0);
      bf16x8 a2 = *(const bf16x8*)(wp + (size_t)(32) * En + k0);
      bf16x8 a3 = *(const bf16x8*)(wp + (size_t)(48) * En + k0);
      acc0 = __builtin_amdgcn_mfma_f32_16x16x32_bf16(a0, bfr, acc0, 0, 0, 0);
      acc1 = __builtin_amdgcn_mfma_f32_16x16x32_bf16(a1, bfr, acc1, 0, 0, 0);
      acc2 = __builtin_amdgcn_mfma_f32_16x16x32_bf16(a2, bfr, acc2, 0, 0, 0);
      acc3 = __builtin_amdgcn_mfma_f32_16x16x32_bf16(a3, bfr, acc3, 0, 0, 0);
    }
  } else {
    const float* xp = (const float*)xv + (size_t)(r0 + l16) * En + quad * 8;
    for (int k0 = 0; k0 < En; k0 += 32) {
      float4 f0 = *(const float4*)(xp + k0);
      float4 f1 = *(const float4*)(xp + k0 + 4);
      bf16x8 bfr;
      bfr[0] = (__bf16)f0.x; bfr[1] = (__bf16)f0.y;
      bfr[2] = (__bf16)f0.z; bfr[3] = (__bf16)f0.w;
      bfr[4] = (__bf16)f1.x; bfr[5] = (__bf16)f1.y;
      bfr[6] = (__bf16)f1.z; bfr[7] = (__bf16)f1.w;
      bf16x8 a0 = *(const bf16x8*)(wp + k0);
      bf16x8 a1 = *(const bf16x8*)(wp + (size_t)(16) * En + k0);
      bf16x8 a2 = *(const bf16x8*)(wp + (size_t)(32) * En + k0);
      bf16x8 a3 = *(const bf16x8*)(wp + (size_t)(48) * En + k0);
      acc0 = __builtin_amdgcn_mfma_f32_16x16x32_bf16(a0, bfr, acc0, 0, 0, 0);
      acc1 = __builtin_amdgcn_mfma_f32_16x16x32_bf16(a1, bfr, acc1, 0, 0, 0);
      acc2 = __builtin_amdgcn_mfma_f32_16x16x32_bf16(a2, bfr, acc2, 0, 0, 0);
      acc3 = __builtin_amdgcn_mfma_f32_16x16x32_bf16(a3, bfr, acc3, 0, 0, 0);
    }
  }

  float* outp = (mat == 0) ? K : (mat == 1) ? Q : V;
  float* dst = outp + (size_t)(r0 + l16) * Hn + quad * 4;
  *(f32x4*)(dst + 0)  = acc0;
  *(f32x4*)(dst + 16) = acc1;
  *(f32x4*)(dst + 32) = acc2;
  *(f32x4*)(dst + 48) = acc3;
}

// ---------- phase 2 (R9): flash attention, all state in named f32x4 SSA vars ----------
// R8's structure/algebra (verified) but NO arrays -> compiler cannot spill to
// scratch (R7/R8 root cause: VGPR_Count 108/32 << live state => scratch round-
// trips each iteration). lane = (query, dim-quarter); 4 waves split keys; LDS
// combine identical to R8.
__global__ __launch_bounds__(256, 4) void attn_kernel(
    const float* __restrict__ Q, const float* __restrict__ K,
    const float* __restrict__ V, float* __restrict__ out) {
  const int idx = blockIdx.x;
  const int b = idx & 7;
  const int t = 127 - (idx >> 3);            // biggest tile first
  const int w = threadIdx.x >> 6, lane = threadIdx.x & 63;
  const int ql = lane >> 2, hq = lane & 3;   // query-in-tile, dim quarter
  const int q_abs = t * 16 + ql;
  const int limit = t * 16 + 16;
  const int ch = ((t + 4) >> 2) * 16;        // per-wave key chunk (mult of 16)
  const int lo = w * ch;
  const int hi_l = min(min(lo + ch, limit), q_abs + 1);
  const float* Kb = K + (size_t)b * Tn * Hn + hq * 16;
  const float* Vb = V + (size_t)b * Tn * Hn + hq * 16;

  f32x4 q0, q1, q2, q3;
  {
    const f32x4* qp = (const f32x4*)(Q + ((size_t)b * Tn + q_abs) * Hn + hq * 16);
    q0 = qp[0] * SCALE_LOG2E;
    q1 = qp[1] * SCALE_LOG2E;
    q2 = qp[2] * SCALE_LOG2E;
    q3 = qp[3] * SCALE_LOG2E;
  }
  f32x4 o0 = {0.f, 0.f, 0.f, 0.f}, o1 = o0, o2 = o0, o3 = o0;
  float m = -3.0e38f, l = 0.f;

  for (int j = lo; j < hi_l; ++j) {
    const f32x4* kr = (const f32x4*)(Kb + (size_t)j * Hn);
    f32x4 d = q0 * kr[0];
    d += q1 * kr[1];
    d += q2 * kr[2];
    d += q3 * kr[3];
    float s = (d.x + d.y) + (d.z + d.w);
    s += __shfl_xor(s, 1);   // sum the 4 dim-quarters of this query
    s += __shfl_xor(s, 2);
    if (s > m) {             // lazy rescale (R7-verified algebra)
      const float ar = __builtin_amdgcn_exp2f(m - s);  // first iter: 0
      m = s;
      l *= ar;
      o0 *= ar; o1 *= ar; o2 *= ar; o3 *= ar;
    }
    const float p = __builtin_amdgcn_exp2f(s - m);
    l += p;
    const f32x4* vr = (const f32x4*)(Vb + (size_t)j * Hn);
    o0 += p * vr[0];
    o1 += p * vr[1];
    o2 += p * vr[2];
    o3 += p * vr[3];
  }

  // ---- cross-wave combine in LDS (algebra identical to verified R8) ----
  __shared__ float m_sh[4][16];
  __shared__ float l_sh[4][16];
  __shared__ f32x4 o_sh[4][16][16];  // [wave][query][dim-group of 4]
  if (hq == 0) { m_sh[w][ql] = m; l_sh[w][ql] = l; }
  {
    f32x4* orow = &o_sh[w][ql][hq * 4];
    orow[0] = o0; orow[1] = o1; orow[2] = o2; orow[3] = o3;
  }
  __syncthreads();

  const int qq = threadIdx.x >> 4, dq = threadIdx.x & 15;
  float mg = m_sh[0][qq];
#pragma unroll
  for (int ww = 1; ww < 4; ++ww) mg = fmaxf(mg, m_sh[ww][qq]);
  float lg = 0.f;
  f32x4 acc = {0.f, 0.f, 0.f, 0.f};
#pragma unroll
  for (int ww = 0; ww < 4; ++ww) {
    const float lw = l_sh[ww][qq];
    if (lw > 0.f) {
      const float a = __builtin_amdgcn_exp2f(m_sh[ww][qq] - mg);
      lg += a * lw;
      acc += a * o_sh[ww][qq][dq];
    }
  }
  acc *= (1.f / lg);
  *(f32x4*)(out + ((size_t)b * Tn + t * 16 + qq) * Hn + dq * 4) = acc;
}

extern "C" void kernel_launch(void* const* d_in, const int* in_sizes, int n_in,
                              void* d_out, int out_size, void* d_ws, size_t ws_size,
                              hipStream_t stream) {
  // Order-agnostic input mapping (R4 proved it selects the documented order).
  const void* x = nullptr;
  const void* Ws[3] = {nullptr, nullptr, nullptr};
  int wj = 0;
  for (int i = 0; i < n_in; ++i) {
    if (in_sizes[i] == Bn * Tn * En) x = d_in[i];
    else if (wj < 3) Ws[wj++] = d_in[i];
  }
  const void* Wk = Ws[0];
  const void* Wq = Ws[1];
  const void* Wv = Ws[2];

  // ws: Q,K,V fp32 [16384][64] (4 MB each) + Wt bf16 (384 KB).
  float* Qf = (float*)d_ws;
  float* Kf = Qf + (size_t)Mrows * Hn;
  float* Vf = Kf + (size_t)Mrows * Hn;
  u16* Wt = (u16*)(Vf + (size_t)Mrows * Hn);

  wt_kernel<<<768, 256, 0, stream>>>(x, Wk, Wq, Wv, Wt);
  qkv_kernel<<<3 * (Mrows / 16), 64, 0, stream>>>(x, Wt, Kf, Qf, Vf);
  attn_kernel<<<Bn * (Tn / 16), 256, 0, stream>>>(Qf, Kf, Vf, (float*)d_out);
}

// Round 10
// 216.178 us; speedup vs baseline: 4.0857x; 3.3502x over previous
//
#include <hip/hip_runtime.h>

typedef unsigned short u16;
typedef unsigned int u32;
typedef __bf16 bf16x8 __attribute__((ext_vector_type(8)));
typedef float f32x4 __attribute__((ext_vector_type(4)));

constexpr int Bn = 8, Tn = 2048, En = 1024, Hn = 64;
constexpr int Mrows = Bn * Tn;  // 16384
// softmax in exp2 domain: p = exp2((s - m) * CEXP), CEXP = E^-0.5 * log2(e)
constexpr float CEXP = 0.03125f * 1.4426950408889634f;

// ---- dtype sniff: packed bf16 vs fp32 (bf16 exponent bits land in [96,144]) ----
__device__ __forceinline__ bool sniff_bf16(const u32* xw) {
  int cnt = 0;
#pragma unroll 1
  for (int i = 0; i < 64; ++i) {
    u32 e = (xw[i] >> 7) & 0xFFu;
    cnt += (e >= 96u && e <= 144u) ? 1 : 0;
  }
  return cnt >= 48;
}

__device__ __forceinline__ u16 f2bf(float f) {  // RNE f32 -> bf16
  u32 u = __float_as_uint(f);
  return (u16)((u + 0x7fffu + ((u >> 16) & 1u)) >> 16);
}

// ---------- phase 0: W [E][H] -> Wt [3][H][E] bf16 (contiguous-k A-frags) ----------
__global__ void wt_kernel(const void* __restrict__ xv, const void* __restrict__ Wkv,
                          const void* __restrict__ Wqv, const void* __restrict__ Wvv,
                          u16* __restrict__ Wt) {
  const bool isbf = sniff_bf16((const u32*)xv);
  int tid = blockIdx.x * 256 + threadIdx.x;  // 3*64*1024 = 196608 exact
  int mat = tid >> 16;
  int rem = tid & 65535;
  int h = rem >> 10, k = rem & 1023;
  const void* W = (mat == 0) ? Wkv : (mat == 1) ? Wqv : Wvv;
  u16 val;
  if (isbf) val = ((const u16*)W)[k * 64 + h];
  else      val = f2bf(((const float*)W)[k * 64 + h]);
  Wt[tid] = val;
}

// ---------- phase 1 (R10): QKV projection (R9-proven loop), bf16 epilogue ----------
// mat 0 -> Kb16 [row][64], mat 1 -> Qb16 [row][64], mat 2 -> Vt16 [b][h][t] (transposed).
__global__ __launch_bounds__(64, 1) void qkv_kernel(
    const void* __restrict__ xv, const u16* __restrict__ Wt,
    u16* __restrict__ Kb16, u16* __restrict__ Qb16, u16* __restrict__ Vt16) {
  const bool isbf = sniff_bf16((const u32*)xv);
  const u32 bx = blockIdx.x;
  const u32 rg = bx / 3u;        // row group 0..1023
  const u32 mat = bx - rg * 3u;  // 0..2
  const int lane = threadIdx.x;
  const int quad = lane >> 4, l16 = lane & 15;
  const int r0 = rg * 16;
  const u16* wp = Wt + (size_t)mat * (Hn * En) + (size_t)l16 * En + quad * 8;
  f32x4 acc0 = {0.f, 0.f, 0.f, 0.f}, acc1 = acc0, acc2 = acc0, acc3 = acc0;

  if (isbf) {
    const u16* xp = (const u16*)xv + (size_t)(r0 + l16) * En + quad * 8;
    for (int k0 = 0; k0 < En; k0 += 32) {
      bf16x8 bfr = *(const bf16x8*)(xp + k0);
      bf16x8 a0 = *(const bf16x8*)(wp + k0);
      bf16x8 a1 = *(const bf16x8*)(wp + (size_t)(16) * En + k0);
      bf16x8 a2 = *(const bf16x8*)(wp + (size_t)(32) * En + k0);
      bf16x8 a3 = *(const bf16x8*)(wp + (size_t)(48) * En + k0);
      acc0 = __builtin_amdgcn_mfma_f32_16x16x32_bf16(a0, bfr, acc0, 0, 0, 0);
      acc1 = __builtin_amdgcn_mfma_f32_16x16x32_bf16(a1, bfr, acc1, 0, 0, 0);
      acc2 = __builtin_amdgcn_mfma_f32_16x16x32_bf16(a2, bfr, acc2, 0, 0, 0);
      acc3 = __builtin_amdgcn_mfma_f32_16x16x32_bf16(a3, bfr, acc3, 0, 0, 0);
    }
  } else {
    const float* xp = (const float*)xv + (size_t)(r0 + l16) * En + quad * 8;
    for (int k0 = 0; k0 < En; k0 += 32) {
      float4 f0 = *(const float4*)(xp + k0);
      float4 f1 = *(const float4*)(xp + k0 + 4);
      bf16x8 bfr;
      bfr[0] = (__bf16)f0.x; bfr[1] = (__bf16)f0.y;
      bfr[2] = (__bf16)f0.z; bfr[3] = (__bf16)f0.w;
      bfr[4] = (__bf16)f1.x; bfr[5] = (__bf16)f1.y;
      bfr[6] = (__bf16)f1.z; bfr[7] = (__bf16)f1.w;
      bf16x8 a0 = *(const bf16x8*)(wp + k0);
      bf16x8 a1 = *(const bf16x8*)(wp + (size_t)(16) * En + k0);
      bf16x8 a2 = *(const bf16x8*)(wp + (size_t)(32) * En + k0);
      bf16x8 a3 = *(const bf16x8*)(wp + (size_t)(48) * En + k0);
      acc0 = __builtin_amdgcn_mfma_f32_16x16x32_bf16(a0, bfr, acc0, 0, 0, 0);
      acc1 = __builtin_amdgcn_mfma_f32_16x16x32_bf16(a1, bfr, acc1, 0, 0, 0);
      acc2 = __builtin_amdgcn_mfma_f32_16x16x32_bf16(a2, bfr, acc2, 0, 0, 0);
      acc3 = __builtin_amdgcn_mfma_f32_16x16x32_bf16(a3, bfr, acc3, 0, 0, 0);
    }
  }

  const int row = r0 + l16;
  if (mat < 2) {
    u16* dst = ((mat == 0) ? Kb16 : Qb16) + (size_t)row * Hn + quad * 4;
    f32x4 a[4] = {acc0, acc1, acc2, acc3};
#pragma unroll
    for (int ti = 0; ti < 4; ++ti) {
      uint2 pk;
      pk.x = (u32)f2bf(a[ti][0]) | ((u32)f2bf(a[ti][1]) << 16);
      pk.y = (u32)f2bf(a[ti][2]) | ((u32)f2bf(a[ti][3]) << 16);
      *(uint2*)(dst + ti * 16) = pk;
    }
  } else {  // V: scatter-transpose into Vt16[b][h][t]
    const int bb = row >> 11, tt = row & 2047;
    u16* base = Vt16 + ((size_t)bb * 64) * Tn + tt;
    f32x4 a[4] = {acc0, acc1, acc2, acc3};
#pragma unroll
    for (int ti = 0; ti < 4; ++ti)
#pragma unroll
      for (int r = 0; r < 4; ++r)
        base[(size_t)(ti * 16 + quad * 4 + r) * Tn] = f2bf(a[ti][r]);
  }
}

// ---------- phase 2 (R10): MFMA flash attention ----------
// 2 waves/block; wave = 16 queries x full causal key range. Per 32-key tile:
// S^T = K·Q^T (4 MFMA, C: row=key=quad*4+reg, col=query=l16), mask, online
// softmax (reduction over keys = regs + shfl_xor 16/32), P->B-frag via 16
// bpermutes (in-wave, no LDS), O^T += V^T·P^T (4 MFMA). No LDS, no barriers.
__global__ __launch_bounds__(128, 2) void attn_kernel(
    const u16* __restrict__ Qb16, const u16* __restrict__ Kb16,
    const u16* __restrict__ Vt16, float* __restrict__ out) {
  const int idx = blockIdx.x;
  const int b = idx & 7;
  const int tq = 63 - (idx >> 3);            // biggest tile first
  const int w = threadIdx.x >> 6, lane = threadIdx.x & 63;
  const int quad = lane >> 4, l16 = lane & 15;
  const int qbase = tq * 32 + w * 16;        // this wave's 16 queries
  const int qmax = qbase + 15;
  const u16* Kp = Kb16 + (size_t)b * Tn * Hn;
  const u16* Vp = Vt16 + (size_t)b * 64 * Tn;

  // Q B-frags (persistent): B[k=quad*8+j][n=l16] = Q[qbase+l16][ks*32+quad*8+j]
  const u16* qrow = Qb16 + ((size_t)b * Tn + qbase + l16) * Hn + quad * 8;
  const bf16x8 qb0 = *(const bf16x8*)(qrow);
  const bf16x8 qb1 = *(const bf16x8*)(qrow + 32);

  f32x4 od0 = {0.f, 0.f, 0.f, 0.f}, od1 = od0, od2 = od0, od3 = od0;
  float m = -3.0e38f, l = 0.f;

  for (int kb = 0; kb <= qmax; kb += 32) {
    // ---- S^T tiles: A = K rows (m=key), B = Q (n=query) ----
    const u16* krow0 = Kp + (size_t)(kb + l16) * Hn + quad * 8;
    const u16* krow1 = krow0 + (size_t)16 * Hn;
    f32x4 z = {0.f, 0.f, 0.f, 0.f};
    f32x4 st0 = __builtin_amdgcn_mfma_f32_16x16x32_bf16(*(const bf16x8*)(krow0), qb0, z, 0, 0, 0);
    st0 = __builtin_amdgcn_mfma_f32_16x16x32_bf16(*(const bf16x8*)(krow0 + 32), qb1, st0, 0, 0, 0);
    f32x4 st1 = __builtin_amdgcn_mfma_f32_16x16x32_bf16(*(const bf16x8*)(krow1), qb0, z, 0, 0, 0);
    st1 = __builtin_amdgcn_mfma_f32_16x16x32_bf16(*(const bf16x8*)(krow1 + 32), qb1, st1, 0, 0, 0);

    // ---- causal mask (key = kb + g*16 + quad*4 + r, query = qbase + l16) ----
    const int q_abs = qbase + l16;
    if (kb + 15 > qbase) {
#pragma unroll
      for (int r = 0; r < 4; ++r)
        if (kb + quad * 4 + r > q_abs) st0[r] = -3.0e38f;
    }
    if (kb + 31 > qbase) {
#pragma unroll
      for (int r = 0; r < 4; ++r)
        if (kb + 16 + quad * 4 + r > q_abs) st1[r] = -3.0e38f;
    }

    // ---- tile max over 32 keys (per query l16) ----
    float tm = fmaxf(fmaxf(fmaxf(st0[0], st0[1]), fmaxf(st0[2], st0[3])),
                     fmaxf(fmaxf(st1[0], st1[1]), fmaxf(st1[2], st1[3])));
    tm = fmaxf(tm, __shfl_xor(tm, 16));
    tm = fmaxf(tm, __shfl_xor(tm, 32));

    const float mn = fmaxf(m, tm);
    const float c = __builtin_amdgcn_exp2f((m - mn) * CEXP);  // first tile: 0
    // ---- p = exp2((s - mn)*CEXP) ----
    f32x4 p0, p1;
#pragma unroll
    for (int r = 0; r < 4; ++r) {
      p0[r] = __builtin_amdgcn_exp2f((st0[r] - mn) * CEXP);
      p1[r] = __builtin_amdgcn_exp2f((st1[r] - mn) * CEXP);
    }
    float ts = (p0[0] + p0[1]) + (p0[2] + p0[3]) + (p1[0] + p1[1]) + (p1[2] + p1[3]);
    ts += __shfl_xor(ts, 16);
    ts += __shfl_xor(ts, 32);
    l = l * c + ts;
    od0 *= c; od1 *= c; od2 *= c; od3 *= c;
    m = mn;

    // ---- transform P (S^T layout) -> PV B-frag: lane needs keys quad*8+jj of query l16 ----
    float pv[8];
#pragma unroll
    for (int jj = 0; jj < 8; ++jj) {
      const int sq = (2 * quad + (jj >> 2)) & 3;  // source quad holding that key
      const int src = sq * 16 + l16;
      const float v0 = __shfl(p0[jj & 3], src, 64);
      const float v1 = __shfl(p1[jj & 3], src, 64);
      pv[jj] = (quad < 2) ? v0 : v1;  // g = quad>>1
    }
    union { bf16x8 v; u32 w4[4]; } pb;
#pragma unroll
    for (int i = 0; i < 4; ++i)
      pb.w4[i] = (u32)f2bf(pv[2 * i]) | ((u32)f2bf(pv[2 * i + 1]) << 16);

    // ---- O^T += V^T · P^T : A = Vt rows (m=dim), B = pb (n=query) ----
    const u16* vrow = Vp + (size_t)l16 * Tn + kb + quad * 8;
    od0 = __builtin_amdgcn_mfma_f32_16x16x32_bf16(*(const bf16x8*)(vrow), pb.v, od0, 0, 0, 0);
    od1 = __builtin_amdgcn_mfma_f32_16x16x32_bf16(*(const bf16x8*)(vrow + (size_t)16 * Tn), pb.v, od1, 0, 0, 0);
    od2 = __builtin_amdgcn_mfma_f32_16x16x32_bf16(*(const bf16x8*)(vrow + (size_t)32 * Tn), pb.v, od2, 0, 0, 0);
    od3 = __builtin_amdgcn_mfma_f32_16x16x32_bf16(*(const bf16x8*)(vrow + (size_t)48 * Tn), pb.v, od3, 0, 0, 0);
  }

  // ---- normalize + store: od C-layout row(d)=md*16+quad*4+reg, col(q)=l16 ----
  const float inv = 1.f / l;
  float* orow = out + ((size_t)b * Tn + qbase + l16) * Hn + quad * 4;
  od0 *= inv; od1 *= inv; od2 *= inv; od3 *= inv;
  *(f32x4*)(orow + 0)  = od0;
  *(f32x4*)(orow + 16) = od1;
  *(f32x4*)(orow + 32) = od2;
  *(f32x4*)(orow + 48) = od3;
}

extern "C" void kernel_launch(void* const* d_in, const int* in_sizes, int n_in,
                              void* d_out, int out_size, void* d_ws, size_t ws_size,
                              hipStream_t stream) {
  // Order-agnostic input mapping (R4 proved it selects the documented order).
  const void* x = nullptr;
  const void* Ws[3] = {nullptr, nullptr, nullptr};
  int wj = 0;
  for (int i = 0; i < n_in; ++i) {
    if (in_sizes[i] == Bn * Tn * En) x = d_in[i];
    else if (wj < 3) Ws[wj++] = d_in[i];
  }
  const void* Wk = Ws[0];
  const void* Wq = Ws[1];
  const void* Wv = Ws[2];

  // ws: Kb16, Qb16, Vt16 bf16 (2 MB each) + Wt bf16 (384 KB)
  u16* Kb16 = (u16*)d_ws;
  u16* Qb16 = Kb16 + (size_t)Mrows * Hn;
  u16* Vt16 = Qb16 + (size_t)Mrows * Hn;
  u16* Wt   = Vt16 + (size_t)Mrows * Hn;

  wt_kernel<<<768, 256, 0, stream>>>(x, Wk, Wq, Wv, Wt);
  qkv_kernel<<<3 * (Mrows / 16), 64, 0, stream>>>(x, Wt, Kb16, Qb16, Vt16);
  attn_kernel<<<Bn * (Tn / 32), 128, 0, stream>>>(Qb16, Kb16, Vt16, (float*)d_out);
}

// Round 11
// 176.677 us; speedup vs baseline: 4.9992x; 1.2236x over previous
//
#include <hip/hip_runtime.h>

typedef unsigned short u16;
typedef unsigned int u32;
typedef __bf16 bf16x8 __attribute__((ext_vector_type(8)));
typedef float f32x4 __attribute__((ext_vector_type(4)));

constexpr int Bn = 8, Tn = 2048, En = 1024, Hn = 64;
constexpr int Mrows = Bn * Tn;  // 16384
// softmax in exp2 domain: p = exp2((s - m) * CEXP), CEXP = E^-0.5 * log2(e)
constexpr float CEXP = 0.03125f * 1.4426950408889634f;

__device__ __forceinline__ u16 f2bf(float f) {  // RNE f32 -> bf16
  u32 u = __float_as_uint(f);
  return (u16)((u + 0x7fffu + ((u >> 16) & 1u)) >> 16);
}

// ---------- phase 0 (R11): W [E][H] fp32 -> Wt [3][H][E] bf16, LDS transpose ----------
// Read coalesced over h (4 float4/thread covers a k-row), transpose in LDS,
// write coalesced over k. Grid = 3 mats x 16 k-blocks.
__global__ __launch_bounds__(256) void wt_kernel(
    const float* __restrict__ Wk, const float* __restrict__ Wq,
    const float* __restrict__ Wv, u16* __restrict__ Wt) {
  __shared__ u16 tile[64][72];  // [h][k_local], stride 72 u16 = 144 B (16-aligned)
  const int mat = blockIdx.x >> 4;
  const int k0 = (blockIdx.x & 15) * 64;
  const float* W = (mat == 0) ? Wk : (mat == 1) ? Wq : Wv;
  const int t = threadIdx.x;
  {
    const int kl = t >> 2;          // 0..63
    const int h0 = (t & 3) * 16;    // 0,16,32,48
    const float4* src = (const float4*)(W + (size_t)(k0 + kl) * Hn + h0);
#pragma unroll
    for (int i = 0; i < 4; ++i) {
      float4 v = src[i];
      tile[h0 + 4 * i + 0][kl] = f2bf(v.x);
      tile[h0 + 4 * i + 1][kl] = f2bf(v.y);
      tile[h0 + 4 * i + 2][kl] = f2bf(v.z);
      tile[h0 + 4 * i + 3][kl] = f2bf(v.w);
    }
  }
  __syncthreads();
  {
    const int hl = t >> 2;          // 0..63
    const int kk = (t & 3) * 16;    // 16 u16 = 32 B per thread
    uint4 a = *(const uint4*)&tile[hl][kk];
    uint4 b = *(const uint4*)&tile[hl][kk + 8];
    u16* dst = Wt + (size_t)mat * Hn * En + (size_t)hl * En + k0 + kk;
    *(uint4*)dst = a;
    *(uint4*)(dst + 8) = b;
  }
}

// ---------- phase 1 (R11): QKV as LDS-staged GEMM, x fetched exactly once ----------
// Block = 256 thr (4 waves), 32 rows, full M=192 (3 mats x 64 h).
// Wave w: m-tiles {3w,3w+1,3w+2} x n-tiles {0,1} -> 6 acc f32x4 (unrolled, no spill).
// x[32 rows][64 k] fp32 -> bf16 staged in LDS (stride 72 pad, uniform banks),
// next chunk prefetched into registers during compute. A-frags from Wt (L2-hot).
// MFMA mapping identical to proven R9/R10. Outputs: Kb16/Qb16 [row][64],
// Vt16 [b][h][t] (R10-proven formats).
__global__ __launch_bounds__(256, 2) void qkv_kernel(
    const float* __restrict__ x, const u16* __restrict__ Wt,
    u16* __restrict__ Kb16, u16* __restrict__ Qb16, u16* __restrict__ Vt16) {
  constexpr int NR = 32, BK = 64, LDK = BK + 8;
  __shared__ u16 xs[NR * LDK];
  const int t = threadIdx.x;
  const int w = t >> 6, lane = t & 63;
  const int quad = lane >> 4, l16 = lane & 15;
  const int r0 = blockIdx.x * NR;

  // staging map: thread -> (row 0..31, 8-fp32 chunk 0..7)
  const int srow = t >> 3, schunk = t & 7;
  const float* xp = x + (size_t)(r0 + srow) * En + schunk * 8;
  u16* xsw = xs + srow * LDK + schunk * 8;

  // A-frag base: row = mt*16 + l16, k-offset quad*8 (proven R9 mapping)
  const u16* wpb = Wt + (size_t)l16 * En + quad * 8;

  f32x4 acc[3][2];
#pragma unroll
  for (int i = 0; i < 3; ++i)
#pragma unroll
    for (int nt = 0; nt < 2; ++nt) acc[i][nt] = (f32x4){0.f, 0.f, 0.f, 0.f};

  float4 pre0 = *(const float4*)(xp);
  float4 pre1 = *(const float4*)(xp + 4);

  for (int k0 = 0; k0 < En; k0 += BK) {
    __syncthreads();  // previous chunk's LDS reads complete
    {
      bf16x8 pk;
      pk[0] = (__bf16)pre0.x; pk[1] = (__bf16)pre0.y;
      pk[2] = (__bf16)pre0.z; pk[3] = (__bf16)pre0.w;
      pk[4] = (__bf16)pre1.x; pk[5] = (__bf16)pre1.y;
      pk[6] = (__bf16)pre1.z; pk[7] = (__bf16)pre1.w;
      *(bf16x8*)xsw = pk;
    }
    __syncthreads();
    if (k0 + BK < En) {  // prefetch next chunk (overlaps compute below)
      pre0 = *(const float4*)(xp + k0 + BK);
      pre1 = *(const float4*)(xp + k0 + BK + 4);
    }
#pragma unroll
    for (int ks = 0; ks < 2; ++ks) {
      bf16x8 b0 = *(const bf16x8*)(xs + l16 * LDK + ks * 32 + quad * 8);
      bf16x8 b1 = *(const bf16x8*)(xs + (16 + l16) * LDK + ks * 32 + quad * 8);
#pragma unroll
      for (int i = 0; i < 3; ++i) {
        const int mt = 3 * w + i;
        bf16x8 a = *(const bf16x8*)(wpb + (size_t)(mt * 16) * En + k0 + ks * 32);
        acc[i][0] = __builtin_amdgcn_mfma_f32_16x16x32_bf16(a, b0, acc[i][0], 0, 0, 0);
        acc[i][1] = __builtin_amdgcn_mfma_f32_16x16x32_bf16(a, b1, acc[i][1], 0, 0, 0);
      }
    }
  }

  // epilogue: C row(m)=quad*4+reg, col(n)=l16 (verified m89)
#pragma unroll
  for (int i = 0; i < 3; ++i) {
    const int mt = 3 * w + i;
    const int mat = mt >> 2, ht = mt & 3;
#pragma unroll
    for (int nt = 0; nt < 2; ++nt) {
      const int row = r0 + nt * 16 + l16;
      f32x4 a = acc[i][nt];
      if (mat < 2) {
        u16* dst = ((mat == 0) ? Kb16 : Qb16) + (size_t)row * Hn + ht * 16 + quad * 4;
        uint2 pk;
        pk.x = (u32)f2bf(a[0]) | ((u32)f2bf(a[1]) << 16);
        pk.y = (u32)f2bf(a[2]) | ((u32)f2bf(a[3]) << 16);
        *(uint2*)dst = pk;
      } else {  // V: scatter-transpose into Vt16[b][h][t] (R10-proven)
        const int bb = row >> 11, tt = row & 2047;
        u16* base = Vt16 + ((size_t)bb * 64) * Tn + tt;
#pragma unroll
        for (int r = 0; r < 4; ++r)
          base[(size_t)(ht * 16 + quad * 4 + r) * Tn] = f2bf(a[r]);
      }
    }
  }
}

// ---------- phase 2: MFMA flash attention (R10-proven, unchanged) ----------
__global__ __launch_bounds__(128, 2) void attn_kernel(
    const u16* __restrict__ Qb16, const u16* __restrict__ Kb16,
    const u16* __restrict__ Vt16, float* __restrict__ out) {
  const int idx = blockIdx.x;
  const int b = idx & 7;
  const int tq = 63 - (idx >> 3);            // biggest tile first
  const int w = threadIdx.x >> 6, lane = threadIdx.x & 63;
  const int quad = lane >> 4, l16 = lane & 15;
  const int qbase = tq * 32 + w * 16;
  const int qmax = qbase + 15;
  const u16* Kp = Kb16 + (size_t)b * Tn * Hn;
  const u16* Vp = Vt16 + (size_t)b * 64 * Tn;

  const u16* qrow = Qb16 + ((size_t)b * Tn + qbase + l16) * Hn + quad * 8;
  const bf16x8 qb0 = *(const bf16x8*)(qrow);
  const bf16x8 qb1 = *(const bf16x8*)(qrow + 32);

  f32x4 od0 = {0.f, 0.f, 0.f, 0.f}, od1 = od0, od2 = od0, od3 = od0;
  float m = -3.0e38f, l = 0.f;

  for (int kb = 0; kb <= qmax; kb += 32) {
    const u16* krow0 = Kp + (size_t)(kb + l16) * Hn + quad * 8;
    const u16* krow1 = krow0 + (size_t)16 * Hn;
    f32x4 z = {0.f, 0.f, 0.f, 0.f};
    f32x4 st0 = __builtin_amdgcn_mfma_f32_16x16x32_bf16(*(const bf16x8*)(krow0), qb0, z, 0, 0, 0);
    st0 = __builtin_amdgcn_mfma_f32_16x16x32_bf16(*(const bf16x8*)(krow0 + 32), qb1, st0, 0, 0, 0);
    f32x4 st1 = __builtin_amdgcn_mfma_f32_16x16x32_bf16(*(const bf16x8*)(krow1), qb0, z, 0, 0, 0);
    st1 = __builtin_amdgcn_mfma_f32_16x16x32_bf16(*(const bf16x8*)(krow1 + 32), qb1, st1, 0, 0, 0);

    const int q_abs = qbase + l16;
    if (kb + 15 > qbase) {
#pragma unroll
      for (int r = 0; r < 4; ++r)
        if (kb + quad * 4 + r > q_abs) st0[r] = -3.0e38f;
    }
    if (kb + 31 > qbase) {
#pragma unroll
      for (int r = 0; r < 4; ++r)
        if (kb + 16 + quad * 4 + r > q_abs) st1[r] = -3.0e38f;
    }

    float tm = fmaxf(fmaxf(fmaxf(st0[0], st0[1]), fmaxf(st0[2], st0[3])),
                     fmaxf(fmaxf(st1[0], st1[1]), fmaxf(st1[2], st1[3])));
    tm = fmaxf(tm, __shfl_xor(tm, 16));
    tm = fmaxf(tm, __shfl_xor(tm, 32));

    const float mn = fmaxf(m, tm);
    const float c = __builtin_amdgcn_exp2f((m - mn) * CEXP);
    f32x4 p0, p1;
#pragma unroll
    for (int r = 0; r < 4; ++r) {
      p0[r] = __builtin_amdgcn_exp2f((st0[r] - mn) * CEXP);
      p1[r] = __builtin_amdgcn_exp2f((st1[r] - mn) * CEXP);
    }
    float ts = (p0[0] + p0[1]) + (p0[2] + p0[3]) + (p1[0] + p1[1]) + (p1[2] + p1[3]);
    ts += __shfl_xor(ts, 16);
    ts += __shfl_xor(ts, 32);
    l = l * c + ts;
    od0 *= c; od1 *= c; od2 *= c; od3 *= c;
    m = mn;

    float pv[8];
#pragma unroll
    for (int jj = 0; jj < 8; ++jj) {
      const int sq = (2 * quad + (jj >> 2)) & 3;
      const int src = sq * 16 + l16;
      const float v0 = __shfl(p0[jj & 3], src, 64);
      const float v1 = __shfl(p1[jj & 3], src, 64);
      pv[jj] = (quad < 2) ? v0 : v1;
    }
    union { bf16x8 v; u32 w4[4]; } pb;
#pragma unroll
    for (int i = 0; i < 4; ++i)
      pb.w4[i] = (u32)f2bf(pv[2 * i]) | ((u32)f2bf(pv[2 * i + 1]) << 16);

    const u16* vrow = Vp + (size_t)l16 * Tn + kb + quad * 8;
    od0 = __builtin_amdgcn_mfma_f32_16x16x32_bf16(*(const bf16x8*)(vrow), pb.v, od0, 0, 0, 0);
    od1 = __builtin_amdgcn_mfma_f32_16x16x32_bf16(*(const bf16x8*)(vrow + (size_t)16 * Tn), pb.v, od1, 0, 0, 0);
    od2 = __builtin_amdgcn_mfma_f32_16x16x32_bf16(*(const bf16x8*)(vrow + (size_t)32 * Tn), pb.v, od2, 0, 0, 0);
    od3 = __builtin_amdgcn_mfma_f32_16x16x32_bf16(*(const bf16x8*)(vrow + (size_t)48 * Tn), pb.v, od3, 0, 0, 0);
  }

  const float inv = 1.f / l;
  float* orow = out + ((size_t)b * Tn + qbase + l16) * Hn + quad * 4;
  od0 *= inv; od1 *= inv; od2 *= inv; od3 *= inv;
  *(f32x4*)(orow + 0)  = od0;
  *(f32x4*)(orow + 16) = od1;
  *(f32x4*)(orow + 32) = od2;
  *(f32x4*)(orow + 48) = od3;
}

extern "C" void kernel_launch(void* const* d_in, const int* in_sizes, int n_in,
                              void* d_out, int out_size, void* d_ws, size_t ws_size,
                              hipStream_t stream) {
  // Order-agnostic input mapping (R4 proved it selects the documented order).
  const void* x = nullptr;
  const void* Ws[3] = {nullptr, nullptr, nullptr};
  int wj = 0;
  for (int i = 0; i < n_in; ++i) {
    if (in_sizes[i] == Bn * Tn * En) x = d_in[i];
    else if (wj < 3) Ws[wj++] = d_in[i];
  }
  const float* Wk = (const float*)Ws[0];
  const float* Wq = (const float*)Ws[1];
  const float* Wv = (const float*)Ws[2];

  // ws: Kb16, Qb16, Vt16 bf16 (2 MB each) + Wt bf16 (384 KB)
  u16* Kb16 = (u16*)d_ws;
  u16* Qb16 = Kb16 + (size_t)Mrows * Hn;
  u16* Vt16 = Qb16 + (size_t)Mrows * Hn;
  u16* Wt   = Vt16 + (size_t)Mrows * Hn;

  wt_kernel<<<48, 256, 0, stream>>>(Wk, Wq, Wv, Wt);
  qkv_kernel<<<Mrows / 32, 256, 0, stream>>>((const float*)x, Wt, Kb16, Qb16, Vt16);
  attn_kernel<<<Bn * (Tn / 32), 128, 0, stream>>>(Qb16, Kb16, Vt16, (float*)d_out);
}

// Round 12
// 159.798 us; speedup vs baseline: 5.5272x; 1.1056x over previous
//
#include <hip/hip_runtime.h>

typedef unsigned short u16;
typedef unsigned int u32;
typedef __bf16 bf16x8 __attribute__((ext_vector_type(8)));
typedef float f32x4 __attribute__((ext_vector_type(4)));

constexpr int Bn = 8, Tn = 2048, En = 1024, Hn = 64;
constexpr int Mrows = Bn * Tn;  // 16384
// softmax in exp2 domain: p = exp2((s - m) * CEXP), CEXP = E^-0.5 * log2(e)
constexpr float CEXP = 0.03125f * 1.4426950408889634f;

__device__ __forceinline__ u16 f2bf(float f) {  // RNE f32 -> bf16
  u32 u = __float_as_uint(f);
  return (u16)((u + 0x7fffu + ((u >> 16) & 1u)) >> 16);
}

// ---------- phase 0 (R11-proven): W [E][H] fp32 -> Wt [3][H][E] bf16 ----------
__global__ __launch_bounds__(256) void wt_kernel(
    const float* __restrict__ Wk, const float* __restrict__ Wq,
    const float* __restrict__ Wv, u16* __restrict__ Wt) {
  __shared__ u16 tile[64][72];
  const int mat = blockIdx.x >> 4;
  const int k0 = (blockIdx.x & 15) * 64;
  const float* W = (mat == 0) ? Wk : (mat == 1) ? Wq : Wv;
  const int t = threadIdx.x;
  {
    const int kl = t >> 2;
    const int h0 = (t & 3) * 16;
    const float4* src = (const float4*)(W + (size_t)(k0 + kl) * Hn + h0);
#pragma unroll
    for (int i = 0; i < 4; ++i) {
      float4 v = src[i];
      tile[h0 + 4 * i + 0][kl] = f2bf(v.x);
      tile[h0 + 4 * i + 1][kl] = f2bf(v.y);
      tile[h0 + 4 * i + 2][kl] = f2bf(v.z);
      tile[h0 + 4 * i + 3][kl] = f2bf(v.w);
    }
  }
  __syncthreads();
  {
    const int hl = t >> 2;
    const int kk = (t & 3) * 16;
    uint4 a = *(const uint4*)&tile[hl][kk];
    uint4 b = *(const uint4*)&tile[hl][kk + 8];
    u16* dst = Wt + (size_t)mat * Hn * En + (size_t)hl * En + k0 + kk;
    *(uint4*)dst = a;
    *(uint4*)(dst + 8) = b;
  }
}

// ---------- phase 1 (R11-proven): QKV as LDS-staged GEMM ----------
__global__ __launch_bounds__(256, 2) void qkv_kernel(
    const float* __restrict__ x, const u16* __restrict__ Wt,
    u16* __restrict__ Kb16, u16* __restrict__ Qb16, u16* __restrict__ Vt16) {
  constexpr int NR = 32, BK = 64, LDK = BK + 8;
  __shared__ u16 xs[NR * LDK];
  const int t = threadIdx.x;
  const int w = t >> 6, lane = t & 63;
  const int quad = lane >> 4, l16 = lane & 15;
  const int r0 = blockIdx.x * NR;

  const int srow = t >> 3, schunk = t & 7;
  const float* xp = x + (size_t)(r0 + srow) * En + schunk * 8;
  u16* xsw = xs + srow * LDK + schunk * 8;

  const u16* wpb = Wt + (size_t)l16 * En + quad * 8;

  f32x4 acc[3][2];
#pragma unroll
  for (int i = 0; i < 3; ++i)
#pragma unroll
    for (int nt = 0; nt < 2; ++nt) acc[i][nt] = (f32x4){0.f, 0.f, 0.f, 0.f};

  float4 pre0 = *(const float4*)(xp);
  float4 pre1 = *(const float4*)(xp + 4);

  for (int k0 = 0; k0 < En; k0 += BK) {
    __syncthreads();
    {
      bf16x8 pk;
      pk[0] = (__bf16)pre0.x; pk[1] = (__bf16)pre0.y;
      pk[2] = (__bf16)pre0.z; pk[3] = (__bf16)pre0.w;
      pk[4] = (__bf16)pre1.x; pk[5] = (__bf16)pre1.y;
      pk[6] = (__bf16)pre1.z; pk[7] = (__bf16)pre1.w;
      *(bf16x8*)xsw = pk;
    }
    __syncthreads();
    if (k0 + BK < En) {
      pre0 = *(const float4*)(xp + k0 + BK);
      pre1 = *(const float4*)(xp + k0 + BK + 4);
    }
#pragma unroll
    for (int ks = 0; ks < 2; ++ks) {
      bf16x8 b0 = *(const bf16x8*)(xs + l16 * LDK + ks * 32 + quad * 8);
      bf16x8 b1 = *(const bf16x8*)(xs + (16 + l16) * LDK + ks * 32 + quad * 8);
#pragma unroll
      for (int i = 0; i < 3; ++i) {
        const int mt = 3 * w + i;
        bf16x8 a = *(const bf16x8*)(wpb + (size_t)(mt * 16) * En + k0 + ks * 32);
        acc[i][0] = __builtin_amdgcn_mfma_f32_16x16x32_bf16(a, b0, acc[i][0], 0, 0, 0);
        acc[i][1] = __builtin_amdgcn_mfma_f32_16x16x32_bf16(a, b1, acc[i][1], 0, 0, 0);
      }
    }
  }

#pragma unroll
  for (int i = 0; i < 3; ++i) {
    const int mt = 3 * w + i;
    const int mat = mt >> 2, ht = mt & 3;
#pragma unroll
    for (int nt = 0; nt < 2; ++nt) {
      const int row = r0 + nt * 16 + l16;
      f32x4 a = acc[i][nt];
      if (mat < 2) {
        u16* dst = ((mat == 0) ? Kb16 : Qb16) + (size_t)row * Hn + ht * 16 + quad * 4;
        uint2 pk;
        pk.x = (u32)f2bf(a[0]) | ((u32)f2bf(a[1]) << 16);
        pk.y = (u32)f2bf(a[2]) | ((u32)f2bf(a[3]) << 16);
        *(uint2*)dst = pk;
      } else {
        const int bb = row >> 11, tt = row & 2047;
        u16* base = Vt16 + ((size_t)bb * 64) * Tn + tt;
#pragma unroll
        for (int r = 0; r < 4; ++r)
          base[(size_t)(ht * 16 + quad * 4 + r) * Tn] = f2bf(a[r]);
      }
    }
  }
}

// ---------- phase 2 (R12): MFMA flash attention, in-block key-split ----------
// Block = 4 waves on ONE 16-query tile; wave w takes a contiguous quarter of
// the causal key range (32-aligned). MFMA structure / layouts / mask identical
// to proven R10. P-transform now a wave-private LDS round-trip (2x ds_write_b64
// + 1x ds_read_b128, no barrier) instead of 16 bpermutes. LDS (m,l,O) combine
// uses the R9-proven algebra. Grid 1024 blocks, biggest tile first.
__global__ __launch_bounds__(256, 4) void attn_kernel(
    const u16* __restrict__ Qb16, const u16* __restrict__ Kb16,
    const u16* __restrict__ Vt16, float* __restrict__ out) {
  __shared__ u16 pt[4][16][40];        // [wave][query][key 0..31 + pad]
  __shared__ float m_sh[4][16];
  __shared__ float l_sh[4][16];
  __shared__ float o_sh[4][16][68];    // [wave][query][dim + pad]

  const int idx = blockIdx.x;
  const int b = idx & 7;
  const int tq = 127 - (idx >> 3);     // biggest tile first
  const int w = threadIdx.x >> 6, lane = threadIdx.x & 63;
  const int quad = lane >> 4, l16 = lane & 15;
  const int qbase = tq * 16;
  const int limit = qbase + 16;        // keys [0, limit)
  const int ch = ((limit + 127) >> 7) << 5;  // per-wave chunk, mult of 32
  const int lo = w * ch;
  const int hi = min(lo + ch, limit);
  const int q_abs = qbase + l16;

  const u16* Kp = Kb16 + (size_t)b * Tn * Hn;
  const u16* Vp = Vt16 + (size_t)b * 64 * Tn;

  const u16* qrow = Qb16 + ((size_t)b * Tn + q_abs) * Hn + quad * 8;
  const bf16x8 qb0 = *(const bf16x8*)(qrow);
  const bf16x8 qb1 = *(const bf16x8*)(qrow + 32);

  f32x4 od0 = {0.f, 0.f, 0.f, 0.f}, od1 = od0, od2 = od0, od3 = od0;
  float m = -3.0e38f, l = 0.f;

  for (int kb = lo; kb < hi; kb += 32) {
    // ---- S^T: A = K rows (m=key), B = Q (n=query) ----
    const u16* krow0 = Kp + (size_t)(kb + l16) * Hn + quad * 8;
    const u16* krow1 = krow0 + (size_t)16 * Hn;
    f32x4 z = {0.f, 0.f, 0.f, 0.f};
    f32x4 st0 = __builtin_amdgcn_mfma_f32_16x16x32_bf16(*(const bf16x8*)(krow0), qb0, z, 0, 0, 0);
    st0 = __builtin_amdgcn_mfma_f32_16x16x32_bf16(*(const bf16x8*)(krow0 + 32), qb1, st0, 0, 0, 0);
    f32x4 st1 = __builtin_amdgcn_mfma_f32_16x16x32_bf16(*(const bf16x8*)(krow1), qb0, z, 0, 0, 0);
    st1 = __builtin_amdgcn_mfma_f32_16x16x32_bf16(*(const bf16x8*)(krow1 + 32), qb1, st1, 0, 0, 0);

    // ---- causal mask (key = kb + g*16 + quad*4 + r) ----
    if (kb + 15 > qbase) {
#pragma unroll
      for (int r = 0; r < 4; ++r)
        if (kb + quad * 4 + r > q_abs) st0[r] = -3.0e38f;
    }
    if (kb + 31 > qbase) {
#pragma unroll
      for (int r = 0; r < 4; ++r)
        if (kb + 16 + quad * 4 + r > q_abs) st1[r] = -3.0e38f;
    }

    // ---- tile max over 32 keys (per query l16) ----
    float tm = fmaxf(fmaxf(fmaxf(st0[0], st0[1]), fmaxf(st0[2], st0[3])),
                     fmaxf(fmaxf(st1[0], st1[1]), fmaxf(st1[2], st1[3])));
    tm = fmaxf(tm, __shfl_xor(tm, 16));
    tm = fmaxf(tm, __shfl_xor(tm, 32));

    const float mn = fmaxf(m, tm);
    const float c = __builtin_amdgcn_exp2f((m - mn) * CEXP);  // first tile: 0
    f32x4 p0, p1;
#pragma unroll
    for (int r = 0; r < 4; ++r) {
      p0[r] = __builtin_amdgcn_exp2f((st0[r] - mn) * CEXP);
      p1[r] = __builtin_amdgcn_exp2f((st1[r] - mn) * CEXP);
    }
    float ts = (p0[0] + p0[1]) + (p0[2] + p0[3]) + (p1[0] + p1[1]) + (p1[2] + p1[3]);
    ts += __shfl_xor(ts, 16);
    ts += __shfl_xor(ts, 32);
    l = l * c + ts;
    od0 *= c; od1 *= c; od2 *= c; od3 *= c;
    m = mn;

    // ---- P (S^T layout) -> PV B-frag via wave-private LDS (no barrier) ----
    // write P^T[query l16][key]: st0 keys quad*4+r, st1 keys 16+quad*4+r
    {
      uint2 w0, w1;
      w0.x = (u32)f2bf(p0[0]) | ((u32)f2bf(p0[1]) << 16);
      w0.y = (u32)f2bf(p0[2]) | ((u32)f2bf(p0[3]) << 16);
      w1.x = (u32)f2bf(p1[0]) | ((u32)f2bf(p1[1]) << 16);
      w1.y = (u32)f2bf(p1[2]) | ((u32)f2bf(p1[3]) << 16);
      *(uint2*)&pt[w][l16][quad * 4] = w0;
      *(uint2*)&pt[w][l16][16 + quad * 4] = w1;
    }
    const bf16x8 pb = *(const bf16x8*)&pt[w][l16][quad * 8];  // B[k=quad*8+j][n=l16]

    // ---- O^T += V^T · P^T ----
    const u16* vrow = Vp + (size_t)l16 * Tn + kb + quad * 8;
    od0 = __builtin_amdgcn_mfma_f32_16x16x32_bf16(*(const bf16x8*)(vrow), pb, od0, 0, 0, 0);
    od1 = __builtin_amdgcn_mfma_f32_16x16x32_bf16(*(const bf16x8*)(vrow + (size_t)16 * Tn), pb, od1, 0, 0, 0);
    od2 = __builtin_amdgcn_mfma_f32_16x16x32_bf16(*(const bf16x8*)(vrow + (size_t)32 * Tn), pb, od2, 0, 0, 0);
    od3 = __builtin_amdgcn_mfma_f32_16x16x32_bf16(*(const bf16x8*)(vrow + (size_t)48 * Tn), pb, od3, 0, 0, 0);
  }

  // ---- cross-wave combine (R9-proven algebra) ----
  if (quad == 0) { m_sh[w][l16] = m; l_sh[w][l16] = l; }
  *(f32x4*)&o_sh[w][l16][0 * 16 + quad * 4] = od0;
  *(f32x4*)&o_sh[w][l16][1 * 16 + quad * 4] = od1;
  *(f32x4*)&o_sh[w][l16][2 * 16 + quad * 4] = od2;
  *(f32x4*)&o_sh[w][l16][3 * 16 + quad * 4] = od3;
  __syncthreads();

  const int qq = threadIdx.x >> 4, dq = threadIdx.x & 15;  // query, dim group
  float mg = m_sh[0][qq];
#pragma unroll
  for (int ww = 1; ww < 4; ++ww) mg = fmaxf(mg, m_sh[ww][qq]);
  float lg = 0.f;
  f32x4 acc = {0.f, 0.f, 0.f, 0.f};
#pragma unroll
  for (int ww = 0; ww < 4; ++ww) {
    const float lw = l_sh[ww][qq];
    if (lw > 0.f) {
      const float a = __builtin_amdgcn_exp2f((m_sh[ww][qq] - mg) * CEXP);
      lg += a * lw;
      acc += a * *(const f32x4*)&o_sh[ww][qq][dq * 4];
    }
  }
  acc *= (1.f / lg);
  *(f32x4*)(out + ((size_t)b * Tn + qbase + qq) * Hn + dq * 4) = acc;
}

extern "C" void kernel_launch(void* const* d_in, const int* in_sizes, int n_in,
                              void* d_out, int out_size, void* d_ws, size_t ws_size,
                              hipStream_t stream) {
  // Order-agnostic input mapping (R4 proved it selects the documented order).
  const void* x = nullptr;
  const void* Ws[3] = {nullptr, nullptr, nullptr};
  int wj = 0;
  for (int i = 0; i < n_in; ++i) {
    if (in_sizes[i] == Bn * Tn * En) x = d_in[i];
    else if (wj < 3) Ws[wj++] = d_in[i];
  }
  const float* Wk = (const float*)Ws[0];
  const float* Wq = (const float*)Ws[1];
  const float* Wv = (const float*)Ws[2];

  // ws: Kb16, Qb16, Vt16 bf16 (2 MB each) + Wt bf16 (384 KB)
  u16* Kb16 = (u16*)d_ws;
  u16* Qb16 = Kb16 + (size_t)Mrows * Hn;
  u16* Vt16 = Qb16 + (size_t)Mrows * Hn;
  u16* Wt   = Vt16 + (size_t)Mrows * Hn;

  wt_kernel<<<48, 256, 0, stream>>>(Wk, Wq, Wv, Wt);
  qkv_kernel<<<Mrows / 32, 256, 0, stream>>>((const float*)x, Wt, Kb16, Qb16, Vt16);
  attn_kernel<<<Bn * (Tn / 16), 256, 0, stream>>>(Qb16, Kb16, Vt16, (float*)d_out);
}